// Round 18
// baseline (67.940 us; speedup 1.0000x reference)
//
#include <hip/hip_runtime.h>
#include <hip/hip_bf16.h>

#define NLVL 16
#define TSZ  16384
#define NB   8

typedef _Float16 h8 __attribute__((ext_vector_type(8)));
typedef float    f4 __attribute__((ext_vector_type(4)));

#define MFMA16(A,B,C) __builtin_amdgcn_mfma_f32_16x16x32_f16(A,B,C,0,0,0)
#define GAINF 1.41421356237309515f

// floor(16 * exp(l*ln(16)/15)); fp64 rounding analysis: l=15 -> 255 (NOT 256).
__device__ const float RES_TAB[16] = {
  16.f, 19.f, 23.f, 27.f, 33.f, 40.f, 48.f, 58.f,
  70.f, 84.f, 101.f, 122.f, 147.f, 176.f, 212.f, 255.f
};

__device__ __forceinline__ float lrelu(float x) {
  float v = x < 0.0f ? 0.2f * x : x;
  return GAINF * v;
}
__device__ __forceinline__ float act(float x) { return fmaxf(x, 0.2f * x); }

__device__ __forceinline__ float tanh_fast(float x) {
  float t = __builtin_amdgcn_exp2f(x * 2.8853900817779268f);  // e^{2x}
  return 1.0f - 2.0f * __builtin_amdgcn_rcpf(t + 1.0f);
}

__device__ __forceinline__ unsigned pk(float a, float b) {
  union { decltype(__builtin_amdgcn_cvt_pkrtz(0.f, 0.f)) h; unsigned u; } U;
  U.h = __builtin_amdgcn_cvt_pkrtz(a, b);
  return U.u;
}
__device__ __forceinline__ unsigned pk_rne(float a, float b) {
  union { _Float16 h[2]; unsigned u; } U;
  U.h[0] = (_Float16)a; U.h[1] = (_Float16)b;
  return U.u;
}

// ---------------- hash-grid features (global path, FUSED fallback) ----------
__device__ __forceinline__ void hash4(const float* __restrict__ bt,
                                      int n, int l0, float* g8)
{
  const float inv = 1.0f / 256.0f;
  float cx = ((n >> 8) + 0.5f) * inv;
  float cy = ((n & 255) + 0.5f) * inv;
#pragma unroll
  for (int j = 0; j < 4; ++j) {
    float res = RES_TAB[l0 + j];
    float px = cx * res, py = cy * res;
    float fx0 = floorf(px), fy0 = floorf(py);
    float fx = px - fx0, fy = py - fy0;
    unsigned x0 = (unsigned)fx0, y0 = (unsigned)fy0;
    unsigned hy0 = y0 * 2654435761u;
    unsigned hy1 = (y0 + 1u) * 2654435761u;
    unsigned i00 = (x0 ^ hy0) & 16383u;
    unsigned i10 = ((x0 + 1u) ^ hy0) & 16383u;
    unsigned i01 = (x0 ^ hy1) & 16383u;
    unsigned i11 = ((x0 + 1u) ^ hy1) & 16383u;
    const float2* tb = (const float2*)(bt + (size_t)(l0 + j) * (TSZ * 2));
    float2 f00 = tb[i00], f10 = tb[i10], f01 = tb[i01], f11 = tb[i11];
    float wx0 = 1.0f - fx, wy0 = 1.0f - fy;
    float w00 = wx0 * wy0, w10 = fx * wy0, w01 = wx0 * fy, w11 = fx * fy;
    g8[2 * j]     = w00 * f00.x + w10 * f10.x + w01 * f01.x + w11 * f11.x;
    g8[2 * j + 1] = w00 * f00.y + w10 * f10.y + w01 * f01.y + w11 * f11.y;
  }
}
__device__ __forceinline__ void hash_features(const float* __restrict__ bt,
                                              int n, float* g)
{
#pragma unroll
  for (int q = 0; q < 4; ++q) hash4(bt, n, q * 4, g + 8 * q);
}

// ---------------- f32 -> f16 slice conversion (128 blocks x 512 thr) --------
__device__ __forceinline__ void cvt2(const float* __restrict__ src,
                                     _Float16* __restrict__ dst,
                                     int n2, int hb, int t)
{
  int cnt = n2 >> 7;                 // pairs per block
  int base = hb * cnt;
  for (int k = t; k < cnt; k += 512) {
    float2 v = ((const float2*)src)[base + k];
    ((unsigned*)dst)[base + k] = pk_rne(v.x, v.y);
  }
}

// ---------------- mapping layer, f16 weights: 16-way split-K, 8-deep --------
// 16B load = 8 halves -> 2x elements in flight at the same byte rate.
__device__ __forceinline__ void map_layer_h(const float* __restrict__ xs_in,
                                            float* __restrict__ out_lds,
                                            const _Float16* __restrict__ Wh,
                                            const float* __restrict__ bias,
                                            int K, int t,
                                            float* __restrict__ part)
{
  const int j8 = (t & 31) * 8;
  const int ks = t >> 5;            // 0..15
  const int chunk = K >> 4;         // 32 (K=512) or 16 (K=256)
  const int kb = ks * chunk;
  f4 acc0 = {0,0,0,0}, acc1 = {0,0,0,0};
  for (int k0 = 0; k0 < chunk; k0 += 8) {
    h8 wr[8];
#pragma unroll
    for (int u = 0; u < 8; ++u)
      wr[u] = *(const h8*)&Wh[(kb + k0 + u) * 256 + j8];
    float xr[8];
#pragma unroll
    for (int u = 0; u < 8; ++u) xr[u] = xs_in[kb + k0 + u];
#pragma unroll
    for (int u = 0; u < 8; ++u) {
      float x = xr[u];
#pragma unroll
      for (int e = 0; e < 4; ++e) {
        acc0[e] = fmaf(x, (float)wr[u][e], acc0[e]);
        acc1[e] = fmaf(x, (float)wr[u][4 + e], acc1[e]);
      }
    }
  }
  *(f4*)&part[ks * 256 + j8] = acc0;
  *(f4*)&part[ks * 256 + j8 + 4] = acc1;
  __syncthreads();
  if (t < 256) {
    float v = 0.f;
#pragma unroll
    for (int q = 0; q < 16; ++q) v += part[q * 256 + t];
    out_lds[t] = lrelu(bias[t] + v);
  }
  __syncthreads();
}

// ---------------- fused pre-pass, 512 threads ---------------------------------
// grid(8 + 128):
//   blocks 8..135 : convert 1/128 of mw0/mw1/mw2 to f16 in ws (~7KB each,
//                   full-chip BW), fence+signal cnt, then hash (LDS table).
//   blocks 0..7   : wait once for cnt==128, then style chain streaming f16
//                   weights (half bytes, 2x elements per load).
__global__ void __launch_bounds__(512) k_pre(
    const float* __restrict__ z,
    const float* __restrict__ mw0, const float* __restrict__ mb0,
    const float* __restrict__ mw1, const float* __restrict__ mb1,
    const float* __restrict__ mw2, const float* __restrict__ mb2,
    const float* __restrict__ bt,
    const float* __restrict__ w_mod, const float* __restrict__ b_mod,
    const float* __restrict__ a0w, const float* __restrict__ a0b,
    const float* __restrict__ w0,
    const float* __restrict__ a1w, const float* __restrict__ a1b,
    const float* __restrict__ w1,
    const float* __restrict__ a2w, const float* __restrict__ a2b,
    const float* __restrict__ w2,
    _Float16* __restrict__ W0h, _Float16* __restrict__ W1h,
    _Float16* __restrict__ W2h, _Float16* __restrict__ ghf,
    _Float16* __restrict__ wh0, _Float16* __restrict__ wh1,
    _Float16* __restrict__ wh2, unsigned* __restrict__ cnt)
{
  __shared__ __align__(16) unsigned smem[16384];   // 64 KB union

  const int t = threadIdx.x;

  if (blockIdx.x >= 8) {
    const int hb = blockIdx.x - 8;      // 0..127

    // ---- convert style weights to f16 (1/128 slice each) ----
    cvt2(mw0, wh0, 65536, hb, t);
    cvt2(mw1, wh1, 32768, hb, t);
    cvt2(mw2, wh2, 32768, hb, t);
    __threadfence();
    __syncthreads();
    if (t == 0) atomicAdd(cnt, 1u);

    // ---- hash: one level per block, f16 table in LDS ----
    const int lvl = hb & 15;
    const int pg  = hb >> 4;
    const int gg  = lvl >> 2;
    const int sub = 2 * (lvl & 3);

    const float4* tb4 = (const float4*)(bt + (size_t)lvl * (TSZ * 2));
#pragma unroll
    for (int i = 0; i < 16; ++i) {
      float4 v = tb4[i * 512 + t];
      int e = (i * 512 + t) * 2;
      smem[e]     = pk_rne(v.x, v.y);
      smem[e + 1] = pk_rne(v.z, v.w);
    }
    __syncthreads();

    const int y = t & 255, xsub = t >> 8;
    const float res = RES_TAB[lvl];
    const float inv = 1.0f / 256.0f;
    float cy = (y + 0.5f) * inv;
    float py = cy * res;
    float fy0 = floorf(py);
    float fy = py - fy0;
    unsigned y0 = (unsigned)fy0;
    unsigned hy0 = y0 * 2654435761u;
    unsigned hy1 = (y0 + 1u) * 2654435761u;
    float wy0 = 1.0f - fy;
    const int cc = y & 15, th = y >> 4;

#pragma unroll
    for (int i = 0; i < 16; ++i) {
      int xo = xsub * 16 + i;
      float cx = (pg * 32 + xo + 0.5f) * inv;
      float px = cx * res;
      float fx0 = floorf(px);
      float fx = px - fx0;
      unsigned x0 = (unsigned)fx0;
      unsigned i00 = (x0 ^ hy0) & 16383u;
      unsigned i10 = ((x0 + 1u) ^ hy0) & 16383u;
      unsigned i01 = (x0 ^ hy1) & 16383u;
      unsigned i11 = ((x0 + 1u) ^ hy1) & 16383u;
      union { unsigned u; _Float16 h[2]; } e00, e10, e01, e11;
      e00.u = smem[i00]; e10.u = smem[i10];
      e01.u = smem[i01]; e11.u = smem[i11];
      float wx0 = 1.0f - fx;
      float w00 = wx0 * wy0, w10 = fx * wy0, w01 = wx0 * fy, w11 = fx * fy;
      float gx = w00 * (float)e00.h[0] + w10 * (float)e10.h[0]
               + w01 * (float)e01.h[0] + w11 * (float)e11.h[0];
      float gy = w00 * (float)e00.h[1] + w10 * (float)e10.h[1]
               + w01 * (float)e01.h[1] + w11 * (float)e11.h[1];
      int tile = pg * 512 + xo * 16 + th;
      *(unsigned*)&ghf[(size_t)tile * 512 + (gg * 16 + cc) * 8 + sub] =
          pk_rne(gx, gy);
    }
    return;
  }

  // ---------------- style chain (f16 weights) ----------------
  float* F    = (float*)smem;
  float* xs   = F;            // 512
  float* sA   = F + 512;      // 256
  float* sB   = F + 768;      // 256
  float* st0  = F + 1024;     // 32
  float* scf  = F + 1056;     // 32
  float* st1  = F + 1088;     // 64
  float* st2  = F + 1152;     // 64
  float* dm0  = F + 1216;     // 64
  float* dm1  = F + 1280;     // 64
  float* dm2  = F + 1344;     // 4
  float* part = F + 2048;     // 4096

  const int b = blockIdx.x;

  xs[t] = z[b * 512 + t];

  // wait once for the f16 weights (producers never block -> no deadlock)
  if (t == 0) {
    while (atomicAdd(cnt, 0u) < 128u) __builtin_amdgcn_s_sleep(8);
    __threadfence();
  }
  __syncthreads();

  map_layer_h(xs, sA, wh0, mb0, 512, t, part);   // layer0
  map_layer_h(sA, sB, wh1, mb1, 256, t, part);   // layer1
  map_layer_h(sB, xs, wh2, mb2, 256, t, part);   // layer2 -> xs[0..255] = s
  const float* ss = xs;

  // ---- proj A: w_mod & a0w (K=256, N=32), fp32, 64 chunks x 4 rows ----
  {
    const int jg = (t & 7) * 4, kc = t >> 3, kb = kc * 4;
    f4 wmr[4], awr[4];
#pragma unroll
    for (int k = 0; k < 4; ++k) wmr[k] = *(const f4*)&w_mod[(kb + k) * 32 + jg];
#pragma unroll
    for (int k = 0; k < 4; ++k) awr[k] = *(const f4*)&a0w[(kb + k) * 32 + jg];
    f4 am = {0,0,0,0}, as = {0,0,0,0};
#pragma unroll
    for (int k = 0; k < 4; ++k) {
      float sv = ss[kb + k];
      am += sv * wmr[k]; as += sv * awr[k];
    }
    *(f4*)&part[kc * 32 + jg] = am;
    *(f4*)&part[2048 + kc * 32 + jg] = as;
  }
  __syncthreads();
  if (t < 32) {
    float am = b_mod[t], as = a0b[t];
#pragma unroll
    for (int q = 0; q < 64; ++q) { am += part[q * 32 + t]; as += part[2048 + q * 32 + t]; }
    scf[t] = 1.0f + am; st0[t] = as;
  }
  __syncthreads();

  // ---- proj B: a1w & a2w (K=256, N=64), fp32, 32 chunks x 8 rows ----
  {
    const int jg = (t & 15) * 4, kc = t >> 4, kb = kc * 8;
    f4 w1r[8], w2r[8];
#pragma unroll
    for (int k = 0; k < 8; ++k) w1r[k] = *(const f4*)&a1w[(kb + k) * 64 + jg];
#pragma unroll
    for (int k = 0; k < 8; ++k) w2r[k] = *(const f4*)&a2w[(kb + k) * 64 + jg];
    f4 v1 = {0,0,0,0}, v2 = {0,0,0,0};
#pragma unroll
    for (int k = 0; k < 8; ++k) {
      float sv = ss[kb + k];
      v1 += sv * w1r[k]; v2 += sv * w2r[k];
    }
    *(f4*)&part[kc * 64 + jg] = v1;
    *(f4*)&part[2048 + kc * 64 + jg] = v2;
  }
  __syncthreads();
  if (t >= 128 && t < 192) {
    int j = t - 128;
    float v1 = a1b[j], v2 = a2b[j];
#pragma unroll
    for (int q = 0; q < 32; ++q) { v1 += part[q * 64 + j]; v2 += part[2048 + q * 64 + j]; }
    st1[j] = v1; st2[j] = v2;
  }
  __syncthreads();

  // ---- demod partials (fp32 w0/w1/w2; tiny streams) ----
  if (t < 256) {
    int j = t & 63, q = t >> 6;
    float wv[8];
#pragma unroll
    for (int i = 0; i < 8; ++i) wv[i] = w0[(q * 8 + i) * 64 + j];
    float acc = (q == 0) ? 1e-8f : 0.f;
#pragma unroll
    for (int i = 0; i < 8; ++i) {
      float p = st0[q * 8 + i] * wv[i]; acc = fmaf(p, p, acc);
    }
    part[t] = acc;
  } else {
    int u = t - 256, j = u & 63, q = u >> 6;
    float wv[16];
#pragma unroll
    for (int k = 0; k < 16; ++k) wv[k] = w1[(q * 16 + k) * 64 + j];
    float acc = (q == 0) ? 1e-8f : 0.f;
#pragma unroll
    for (int k = 0; k < 16; ++k) {
      float p = st1[q * 16 + k] * wv[k]; acc = fmaf(p, p, acc);
    }
    part[256 + u] = acc;
  }
  if (t < 64) {
    int ch = t & 3, q = t >> 2;
    if (ch < 3) {
      float wv[4];
#pragma unroll
      for (int k = 0; k < 4; ++k) wv[k] = w2[(q * 4 + k) * 3 + ch];
      float acc = (q == 0) ? 1e-8f : 0.f;
#pragma unroll
      for (int k = 0; k < 4; ++k) {
        float p = st2[q * 4 + k] * wv[k]; acc = fmaf(p, p, acc);
      }
      part[512 + t] = acc;
    }
  }
  __syncthreads();
  if (t < 64) {
    float a = part[t] + part[64 + t] + part[128 + t] + part[192 + t];
    dm0[t] = 1.0f / sqrtf(a);
  } else if (t < 128) {
    int j = t - 64; float a = 0.f;
#pragma unroll
    for (int q = 0; q < 4; ++q) a += part[256 + q * 64 + j];
    dm1[j] = 1.0f / sqrtf(a);
  } else if (t >= 192 && t < 195) {
    int ch = t - 192; float a = 0.f;
#pragma unroll
    for (int q = 0; q < 16; ++q) a += part[512 + q * 4 + ch];
    dm2[ch] = 1.0f / sqrtf(a);
  }
  __syncthreads();

  // ---- fold effective f16 weights ----
  for (int f = t; f < 2048; f += 512) {
    int j = f >> 5, i = f & 31;
    W0h[b * 2048 + f] = (_Float16)(scf[i] * st0[i] * w0[i * 64 + j] * dm0[j]);
  }
  for (int f = t; f < 4096; f += 512) {
    int j2 = f >> 6, k = f & 63;
    W1h[b * 4096 + f] = (_Float16)(GAINF * st1[k] * w1[k * 64 + j2] * dm1[j2]);
  }
  for (int f = t; f < 1024; f += 512) {
    int ch = f >> 6, k = f & 63;
    W2h[b * 1024 + f] = (ch < 3) ? (_Float16)(GAINF * st2[k] * w2[k * 3 + ch] * dm2[ch])
                                 : (_Float16)0.0f;
  }
}

// ============ fallback single-kernel style (small ws), fp32 =================
__device__ __forceinline__ void map_layer(const float* __restrict__ xs_in,
                                          float* __restrict__ out_lds,
                                          const float* __restrict__ W,
                                          const float* __restrict__ bias,
                                          int K, int t,
                                          float* __restrict__ part)
{
  const int j4 = (t & 63) * 4;
  const int ks = t >> 6;
  const int chunk = K >> 3;
  const int kb = ks * chunk;
  f4 a0 = {0,0,0,0}, a1 = {0,0,0,0}, a2 = {0,0,0,0}, a3 = {0,0,0,0};
  for (int k0 = 0; k0 < chunk; k0 += 8) {
    f4 wr[8];
#pragma unroll
    for (int u = 0; u < 8; ++u)
      wr[u] = *(const f4*)&W[(kb + k0 + u) * 256 + j4];
    float xr[8];
#pragma unroll
    for (int u = 0; u < 8; ++u) xr[u] = xs_in[kb + k0 + u];
#pragma unroll
    for (int u = 0; u < 8; u += 4) {
      a0 += xr[u + 0] * wr[u + 0];
      a1 += xr[u + 1] * wr[u + 1];
      a2 += xr[u + 2] * wr[u + 2];
      a3 += xr[u + 3] * wr[u + 3];
    }
  }
  *(f4*)&part[ks * 256 + j4] = (a0 + a1) + (a2 + a3);
  __syncthreads();
  if (t < 256) {
    float v = 0.f;
#pragma unroll
    for (int q = 0; q < 8; ++q) v += part[q * 256 + t];
    out_lds[t] = lrelu(bias[t] + v);
  }
  __syncthreads();
}

__global__ void __launch_bounds__(512) k_style1(
    const float* __restrict__ z,
    const float* __restrict__ mw0, const float* __restrict__ mb0,
    const float* __restrict__ mw1, const float* __restrict__ mb1,
    const float* __restrict__ mw2, const float* __restrict__ mb2,
    const float* __restrict__ w_mod, const float* __restrict__ b_mod,
    const float* __restrict__ a0w, const float* __restrict__ a0b,
    const float* __restrict__ w0,
    const float* __restrict__ a1w, const float* __restrict__ a1b,
    const float* __restrict__ w1,
    const float* __restrict__ a2w, const float* __restrict__ a2b,
    const float* __restrict__ w2,
    _Float16* __restrict__ W0h, _Float16* __restrict__ W1h,
    _Float16* __restrict__ W2h)
{
  __shared__ __align__(16) float F[8192];
  float* xs   = F;
  float* sA   = F + 512;
  float* sB   = F + 768;
  float* st0  = F + 1024;
  float* scf  = F + 1056;
  float* st1  = F + 1088;
  float* st2  = F + 1152;
  float* dm0  = F + 1216;
  float* dm1  = F + 1280;
  float* dm2  = F + 1344;
  float* part = F + 2048;
  const int t = threadIdx.x;
  const int b = blockIdx.x;

  xs[t] = z[b * 512 + t];
  __syncthreads();
  map_layer(xs, sA, mw0, mb0, 512, t, part);
  map_layer(sA, sB, mw1, mb1, 256, t, part);
  map_layer(sB, xs, mw2, mb2, 256, t, part);
  const float* ss = xs;

  {
    const int jg = (t & 7) * 4, kc = t >> 3, kb = kc * 4;
    f4 am = {0,0,0,0}, as = {0,0,0,0};
#pragma unroll
    for (int k = 0; k < 4; ++k) {
      float sv = ss[kb + k];
      am += sv * *(const f4*)&w_mod[(kb + k) * 32 + jg];
      as += sv * *(const f4*)&a0w[(kb + k) * 32 + jg];
    }
    *(f4*)&part[kc * 32 + jg] = am;
    *(f4*)&part[2048 + kc * 32 + jg] = as;
  }
  __syncthreads();
  if (t < 32) {
    float am = b_mod[t], as = a0b[t];
#pragma unroll
    for (int q = 0; q < 64; ++q) { am += part[q * 32 + t]; as += part[2048 + q * 32 + t]; }
    scf[t] = 1.0f + am; st0[t] = as;
  }
  __syncthreads();
  {
    const int jg = (t & 15) * 4, kc = t >> 4, kb = kc * 8;
    f4 v1 = {0,0,0,0}, v2 = {0,0,0,0};
#pragma unroll
    for (int k = 0; k < 8; ++k) {
      float sv = ss[kb + k];
      v1 += sv * *(const f4*)&a1w[(kb + k) * 64 + jg];
      v2 += sv * *(const f4*)&a2w[(kb + k) * 64 + jg];
    }
    *(f4*)&part[kc * 64 + jg] = v1;
    *(f4*)&part[2048 + kc * 64 + jg] = v2;
  }
  __syncthreads();
  if (t >= 128 && t < 192) {
    int jj = t - 128;
    float v1 = a1b[jj], v2 = a2b[jj];
#pragma unroll
    for (int q = 0; q < 32; ++q) { v1 += part[q * 64 + jj]; v2 += part[2048 + q * 64 + jj]; }
    st1[jj] = v1; st2[jj] = v2;
  }
  __syncthreads();
  if (t < 64) {
    float acc = 1e-8f;
    for (int i = 0; i < 32; ++i) { float p = st0[i] * w0[i * 64 + t]; acc = fmaf(p, p, acc); }
    dm0[t] = 1.0f / sqrtf(acc);
  } else if (t < 128) {
    int jj = t - 64; float acc = 1e-8f;
    for (int k = 0; k < 64; ++k) { float p = st1[k] * w1[k * 64 + jj]; acc = fmaf(p, p, acc); }
    dm1[jj] = 1.0f / sqrtf(acc);
  } else if (t >= 192 && t < 195) {
    int ch = t - 192; float acc = 1e-8f;
    for (int k = 0; k < 64; ++k) { float p = st2[k] * w2[k * 3 + ch]; acc = fmaf(p, p, acc); }
    dm2[ch] = 1.0f / sqrtf(acc);
  }
  __syncthreads();
  for (int f = t; f < 2048; f += 512) {
    int jw = f >> 5, i = f & 31;
    W0h[b * 2048 + f] = (_Float16)(scf[i] * st0[i] * w0[i * 64 + jw] * dm0[jw]);
  }
  for (int f = t; f < 4096; f += 512) {
    int j2 = f >> 6, k = f & 63;
    W1h[b * 4096 + f] = (_Float16)(GAINF * st1[k] * w1[k * 64 + j2] * dm1[j2]);
  }
  for (int f = t; f < 1024; f += 512) {
    int ch = f >> 6, k = f & 63;
    W2h[b * 1024 + f] = (ch < 3) ? (_Float16)(GAINF * st2[k] * w2[k * 3 + ch] * dm2[ch])
                                 : (_Float16)0.0f;
  }
}

// ---------------- LDS activation staging helpers ----------------------------
__device__ __forceinline__ void st4(_Float16* L, int pix, int jb, f4 v) {
  int ks = jb ^ ((pix & 7) << 3);
  union { unsigned u[2]; uint2 v2; } U;
  U.u[0] = pk(v[0], v[1]); U.u[1] = pk(v[2], v[3]);
  *(uint2*)(L + pix * 64 + ks) = U.v2;
}
__device__ __forceinline__ h8 ldf(const _Float16* L, int pix, int kb) {
  int ks = kb ^ ((pix & 7) << 3);
  return *(const h8*)(L + pix * 64 + ks);
}

// ---------------- MFMA MLP ---------------------------------------------------
template <int FUSED>
__global__ void __launch_bounds__(256) k_mlp(
    const _Float16* __restrict__ W0h, const _Float16* __restrict__ W1h,
    const _Float16* __restrict__ W2h, const _Float16* __restrict__ ghf,
    const float* __restrict__ bt,
    const float* __restrict__ bb0, const float* __restrict__ bb1,
    const float* __restrict__ bb2, float* __restrict__ out)
{
  __shared__ _Float16 lds[4][4096];
  __shared__ _Float16 hb[FUSED ? 8192 : 8];

  const int t = threadIdx.x;
  const int w = t >> 6, lane = t & 63;
  const int c = lane & 15, g = lane >> 4;
  const int b = blockIdx.y;
  const int pixb = blockIdx.x * 256 + w * 64;
  const int tile0 = pixb >> 4;
  _Float16* L = lds[w];

  if constexpr (FUSED) {
    float gl[32];
    hash_features(bt, blockIdx.x * 256 + t, gl);
    int tl = t >> 4, cl = t & 15;
#pragma unroll
    for (int gg = 0; gg < 4; ++gg) {
      union { unsigned u[4]; uint4 v; } U;
      U.u[0] = pk(gl[8 * gg + 0], gl[8 * gg + 1]);
      U.u[1] = pk(gl[8 * gg + 2], gl[8 * gg + 3]);
      U.u[2] = pk(gl[8 * gg + 4], gl[8 * gg + 5]);
      U.u[3] = pk(gl[8 * gg + 6], gl[8 * gg + 7]);
      *(uint4*)&hb[tl * 512 + (gg * 16 + cl) * 8] = U.v;
    }
    __syncthreads();
  }

  h8 A0[4], A1[4][2], A2[2];
#pragma unroll
  for (int jt = 0; jt < 4; ++jt)
    A0[jt] = *(const h8*)&W0h[b * 2048 + (jt * 16 + c) * 32 + 8 * g];
#pragma unroll
  for (int jt = 0; jt < 4; ++jt)
#pragma unroll
    for (int kf = 0; kf < 2; ++kf)
      A1[jt][kf] = *(const h8*)&W1h[b * 4096 + (jt * 16 + c) * 64 + kf * 32 + 8 * g];
#pragma unroll
  for (int kf = 0; kf < 2; ++kf)
    A2[kf] = *(const h8*)&W2h[b * 1024 + c * 64 + kf * 32 + 8 * g];

  f4 bv0[4], bv1[4], bv2;
#pragma unroll
  for (int jt = 0; jt < 4; ++jt) {
    bv0[jt] = *(const f4*)&bb0[jt * 16 + 4 * g];
    bv1[jt] = *(const f4*)&bb1[jt * 16 + 4 * g];
  }
  if (g == 0) { bv2 = f4{bb2[0], bb2[1], bb2[2], 0.0f}; }
  else        { bv2 = f4{0.0f, 0.0f, 0.0f, 0.0f}; }

  f4 acc[4][4];
#pragma unroll
  for (int pt = 0; pt < 4; ++pt) {
    h8 Bh;
    if constexpr (FUSED) {
      Bh = *(const h8*)&hb[(w * 4 + pt) * 512 + lane * 8];
    } else {
      Bh = *(const h8*)&ghf[(size_t)(tile0 + pt) * 512 + lane * 8];
    }
#pragma unroll
    for (int jt = 0; jt < 4; ++jt)
      acc[jt][pt] = MFMA16(A0[jt], Bh, bv0[jt]);
  }

#pragma unroll
  for (int jt = 0; jt < 4; ++jt)
#pragma unroll
    for (int pt = 0; pt < 4; ++pt) {
      f4 v = acc[jt][pt];
#pragma unroll
      for (int r = 0; r < 4; ++r) v[r] = act(v[r]);
      st4(L, pt * 16 + c, jt * 16 + 4 * g, v);
    }

  f4 acc1[4][4];
#pragma unroll
  for (int pt = 0; pt < 4; ++pt) {
    h8 Bf0 = ldf(L, pt * 16 + c, 0 * 32 + 8 * g);
    h8 Bf1 = ldf(L, pt * 16 + c, 1 * 32 + 8 * g);
#pragma unroll
    for (int jt = 0; jt < 4; ++jt) {
      f4 a = MFMA16(A1[jt][0], Bf0, bv1[jt]);
      acc1[jt][pt] = MFMA16(A1[jt][1], Bf1, a);
    }
  }

#pragma unroll
  for (int jt = 0; jt < 4; ++jt)
#pragma unroll
    for (int pt = 0; pt < 4; ++pt) {
      f4 v = acc1[jt][pt];
#pragma unroll
      for (int r = 0; r < 4; ++r) v[r] = act(v[r]);
      st4(L, pt * 16 + c, jt * 16 + 4 * g, v);
    }

#pragma unroll
  for (int pt = 0; pt < 4; ++pt) {
    h8 Bf0 = ldf(L, pt * 16 + c, 0 * 32 + 8 * g);
    h8 Bf1 = ldf(L, pt * 16 + c, 1 * 32 + 8 * g);
    f4 a = MFMA16(A2[0], Bf0, bv2);
    a = MFMA16(A2[1], Bf1, a);
    if (g == 0) {
      int pix = pixb + pt * 16 + c;
#pragma unroll
      for (int r = 0; r < 3; ++r)
        out[((b * 3 + r) << 16) + pix] = tanh_fast(a[r]);
    }
  }
}

// ---------------- launch -----------------------------------------------------
// ws bytes: [0,32768) W0h | [32768,98304) W1h | [98304,114688) W2h |
//   [114688,4308992) ghf | [4308992,4571136) wh0 (f16 512x256) |
//   [4571136,4702208) wh1 | [4702208,4833280) wh2 |
//   [4833280,4833288) done counter (memset each call)
extern "C" void kernel_launch(void* const* d_in, const int* in_sizes, int n_in,
                              void* d_out, int out_size, void* d_ws, size_t ws_size,
                              hipStream_t stream)
{
  const float* z    = (const float*)d_in[0];
  const float* mw0  = (const float*)d_in[1];
  const float* mb0  = (const float*)d_in[2];
  const float* mw1  = (const float*)d_in[3];
  const float* mb1  = (const float*)d_in[4];
  const float* mw2  = (const float*)d_in[5];
  const float* mb2  = (const float*)d_in[6];
  const float* bt   = (const float*)d_in[7];
  const float* wmod = (const float*)d_in[8];
  const float* bmod = (const float*)d_in[9];
  const float* a0w  = (const float*)d_in[10];
  const float* a0b  = (const float*)d_in[11];
  const float* w0   = (const float*)d_in[12];
  const float* bb0  = (const float*)d_in[13];
  const float* a1w  = (const float*)d_in[14];
  const float* a1b  = (const float*)d_in[15];
  const float* w1   = (const float*)d_in[16];
  const float* bb1  = (const float*)d_in[17];
  const float* a2w  = (const float*)d_in[18];
  const float* a2b  = (const float*)d_in[19];
  const float* w2   = (const float*)d_in[20];
  const float* bb2  = (const float*)d_in[21];

  char* ws = (char*)d_ws;
  _Float16* W0h = (_Float16*)(ws);
  _Float16* W1h = (_Float16*)(ws + 32768);
  _Float16* W2h = (_Float16*)(ws + 98304);
  _Float16* ghf = (_Float16*)(ws + 114688);
  _Float16* wh0 = (_Float16*)(ws + 4308992);
  _Float16* wh1 = (_Float16*)(ws + 4571136);
  _Float16* wh2 = (_Float16*)(ws + 4702208);
  unsigned* cnt = (unsigned*)(ws + 4833280);
  float* out = (float*)d_out;

  if (ws_size >= (size_t)4833288) {
    hipMemsetAsync(cnt, 0, 8, stream);
    k_pre<<<8 + 128, 512, 0, stream>>>(z, mw0, mb0, mw1, mb1, mw2, mb2, bt,
                                       wmod, bmod, a0w, a0b, w0,
                                       a1w, a1b, w1, a2w, a2b, w2,
                                       W0h, W1h, W2h, ghf, wh0, wh1, wh2, cnt);
    k_mlp<0><<<dim3(256, NB), 256, 0, stream>>>(W0h, W1h, W2h, ghf, bt,
                                                bb0, bb1, bb2, out);
  } else {
    k_style1<<<NB, 512, 0, stream>>>(z, mw0, mb0, mw1, mb1, mw2, mb2,
                                     wmod, bmod, a0w, a0b, w0,
                                     a1w, a1b, w1, a2w, a2b, w2,
                                     W0h, W1h, W2h);
    k_mlp<1><<<dim3(256, NB), 256, 0, stream>>>(W0h, W1h, W2h, ghf, bt,
                                                bb0, bb1, bb2, out);
  }
}

// Round 19
// 42.056 us; speedup vs baseline: 1.6154x; 1.6154x over previous
//
#include <hip/hip_runtime.h>
#include <hip/hip_bf16.h>

#define NLVL 16
#define TSZ  16384
#define NB   8

typedef _Float16 h8 __attribute__((ext_vector_type(8)));
typedef float    f4 __attribute__((ext_vector_type(4)));

#define MFMA16(A,B,C) __builtin_amdgcn_mfma_f32_16x16x32_f16(A,B,C,0,0,0)
#define GAINF 1.41421356237309515f

// floor(16 * exp(l*ln(16)/15)); fp64 rounding analysis: l=15 -> 255 (NOT 256).
__device__ const float RES_TAB[16] = {
  16.f, 19.f, 23.f, 27.f, 33.f, 40.f, 48.f, 58.f,
  70.f, 84.f, 101.f, 122.f, 147.f, 176.f, 212.f, 255.f
};

__device__ __forceinline__ float lrelu(float x) {
  float v = x < 0.0f ? 0.2f * x : x;
  return GAINF * v;
}
__device__ __forceinline__ float act(float x) { return fmaxf(x, 0.2f * x); }

__device__ __forceinline__ float tanh_fast(float x) {
  float t = __builtin_amdgcn_exp2f(x * 2.8853900817779268f);  // e^{2x}
  return 1.0f - 2.0f * __builtin_amdgcn_rcpf(t + 1.0f);
}

__device__ __forceinline__ unsigned pk(float a, float b) {
  union { decltype(__builtin_amdgcn_cvt_pkrtz(0.f, 0.f)) h; unsigned u; } U;
  U.h = __builtin_amdgcn_cvt_pkrtz(a, b);
  return U.u;
}
__device__ __forceinline__ unsigned pk_rne(float a, float b) {
  union { _Float16 h[2]; unsigned u; } U;
  U.h[0] = (_Float16)a; U.h[1] = (_Float16)b;
  return U.u;
}

// ---------------- hash-grid features (global path, FUSED fallback) ----------
__device__ __forceinline__ void hash4(const float* __restrict__ bt,
                                      int n, int l0, float* g8)
{
  const float inv = 1.0f / 256.0f;
  float cx = ((n >> 8) + 0.5f) * inv;
  float cy = ((n & 255) + 0.5f) * inv;
#pragma unroll
  for (int j = 0; j < 4; ++j) {
    float res = RES_TAB[l0 + j];
    float px = cx * res, py = cy * res;
    float fx0 = floorf(px), fy0 = floorf(py);
    float fx = px - fx0, fy = py - fy0;
    unsigned x0 = (unsigned)fx0, y0 = (unsigned)fy0;
    unsigned hy0 = y0 * 2654435761u;
    unsigned hy1 = (y0 + 1u) * 2654435761u;
    unsigned i00 = (x0 ^ hy0) & 16383u;
    unsigned i10 = ((x0 + 1u) ^ hy0) & 16383u;
    unsigned i01 = (x0 ^ hy1) & 16383u;
    unsigned i11 = ((x0 + 1u) ^ hy1) & 16383u;
    const float2* tb = (const float2*)(bt + (size_t)(l0 + j) * (TSZ * 2));
    float2 f00 = tb[i00], f10 = tb[i10], f01 = tb[i01], f11 = tb[i11];
    float wx0 = 1.0f - fx, wy0 = 1.0f - fy;
    float w00 = wx0 * wy0, w10 = fx * wy0, w01 = wx0 * fy, w11 = fx * fy;
    g8[2 * j]     = w00 * f00.x + w10 * f10.x + w01 * f01.x + w11 * f11.x;
    g8[2 * j + 1] = w00 * f00.y + w10 * f10.y + w01 * f01.y + w11 * f11.y;
  }
}
__device__ __forceinline__ void hash_features(const float* __restrict__ bt,
                                              int n, float* g)
{
#pragma unroll
  for (int q = 0; q < 4; ++q) hash4(bt, n, q * 4, g + 8 * q);
}

// ---------------- L2 prefetch: slice s of 16 ------------------------------
__device__ __forceinline__ void pf16(const float* __restrict__ p, int nf4,
                                     int s, int t, uint2& sink)
{
  int per = nf4 >> 4;
  const uint4* q = (const uint4*)p + (size_t)s * per;
  for (int e = t; e < per; e += 512) {
    uint4 v = q[e];
    sink.x ^= v.x; sink.y ^= v.w;
  }
}

// ---------------- mapping layer: 512 thr, 8-way split-K, 8-deep batches -----
__device__ __forceinline__ void map_layer(const float* __restrict__ xs_in,
                                          float* __restrict__ out_lds,
                                          const float* __restrict__ W,
                                          const float* __restrict__ bias,
                                          int K, int t,
                                          float* __restrict__ part)
{
  const int j4 = (t & 63) * 4;
  const int ks = t >> 6;            // 0..7
  const int chunk = K >> 3;         // 64 (K=512) or 32 (K=256)
  const int kb = ks * chunk;
  f4 a0 = {0,0,0,0}, a1 = {0,0,0,0}, a2 = {0,0,0,0}, a3 = {0,0,0,0};
  for (int k0 = 0; k0 < chunk; k0 += 8) {
    f4 wr[8];
#pragma unroll
    for (int u = 0; u < 8; ++u)
      wr[u] = *(const f4*)&W[(kb + k0 + u) * 256 + j4];
    float xr[8];
#pragma unroll
    for (int u = 0; u < 8; ++u) xr[u] = xs_in[kb + k0 + u];
#pragma unroll
    for (int u = 0; u < 8; u += 4) {
      a0 += xr[u + 0] * wr[u + 0];
      a1 += xr[u + 1] * wr[u + 1];
      a2 += xr[u + 2] * wr[u + 2];
      a3 += xr[u + 3] * wr[u + 3];
    }
  }
  *(f4*)&part[ks * 256 + j4] = (a0 + a1) + (a2 + a3);
  __syncthreads();
  if (t < 256) {
    float v = 0.f;
#pragma unroll
    for (int q = 0; q < 8; ++q) v += part[q * 256 + t];
    out_lds[t] = lrelu(bias[t] + v);
  }
  __syncthreads();
}

// ---------------- fused pre-pass, 512 threads ---------------------------------
// grid(8 + 128):
//   blocks 0..7   : style chain (deep-pipelined f4 loads, 128-VGPR budget)
//   blocks 8..135 : prefetch weight slice (hb>>3: one block per XCD per slice)
//                   then hash via LDS-staged f16 table, 16 px/thread
__global__ void __launch_bounds__(512) k_pre(
    const float* __restrict__ z,
    const float* __restrict__ mw0, const float* __restrict__ mb0,
    const float* __restrict__ mw1, const float* __restrict__ mb1,
    const float* __restrict__ mw2, const float* __restrict__ mb2,
    const float* __restrict__ bt,
    const float* __restrict__ w_mod, const float* __restrict__ b_mod,
    const float* __restrict__ a0w, const float* __restrict__ a0b,
    const float* __restrict__ w0,
    const float* __restrict__ a1w, const float* __restrict__ a1b,
    const float* __restrict__ w1,
    const float* __restrict__ a2w, const float* __restrict__ a2b,
    const float* __restrict__ w2,
    _Float16* __restrict__ W0h, _Float16* __restrict__ W1h,
    _Float16* __restrict__ W2h, _Float16* __restrict__ ghf)
{
  __shared__ __align__(16) unsigned smem[16384];   // 64 KB union

  const int t = threadIdx.x;

  if (blockIdx.x >= 8) {
    const int hb  = blockIdx.x - 8;     // 0..127
    // ---- L2 prefetch: slice hb>>3 (16 slices x 8 blocks = all 8 XCDs) ----
    {
      int s = hb >> 3;
      uint2 sink = {0, 0};
      pf16(mw0,  32768, s, t, sink);
      pf16(mw1,  16384, s, t, sink);
      pf16(mw2,  16384, s, t, sink);
      pf16(w_mod, 2048, s, t, sink);
      pf16(a0w,   2048, s, t, sink);
      pf16(a1w,   4096, s, t, sink);
      pf16(a2w,   4096, s, t, sink);
      pf16(w0,     512, s, t, sink);
      pf16(w1,    1024, s, t, sink);
      asm volatile("" :: "v"(sink.x), "v"(sink.y));
    }

    // ---- hash: one level per block, f16-pair table in LDS ----
    const int lvl = hb & 15;
    const int pg  = hb >> 4;            // x columns [pg*32, pg*32+32)
    const int gg  = lvl >> 2;
    const int sub = 2 * (lvl & 3);

    const float4* tb4 = (const float4*)(bt + (size_t)lvl * (TSZ * 2));
#pragma unroll
    for (int i = 0; i < 16; ++i) {      // 8192 float4 / 512 threads
      float4 v = tb4[i * 512 + t];
      int e = (i * 512 + t) * 2;
      smem[e]     = pk_rne(v.x, v.y);
      smem[e + 1] = pk_rne(v.z, v.w);
    }
    __syncthreads();

    const int y = t & 255, xsub = t >> 8;     // xsub 0..1
    const float res = RES_TAB[lvl];
    const float inv = 1.0f / 256.0f;
    float cy = (y + 0.5f) * inv;
    float py = cy * res;
    float fy0 = floorf(py);
    float fy = py - fy0;
    unsigned y0 = (unsigned)fy0;
    unsigned hy0 = y0 * 2654435761u;
    unsigned hy1 = (y0 + 1u) * 2654435761u;
    float wy0 = 1.0f - fy;
    const int cc = y & 15, th = y >> 4;

#pragma unroll
    for (int i = 0; i < 16; ++i) {
      int xo = xsub * 16 + i;                 // 0..31
      float cx = (pg * 32 + xo + 0.5f) * inv;
      float px = cx * res;
      float fx0 = floorf(px);
      float fx = px - fx0;
      unsigned x0 = (unsigned)fx0;
      unsigned i00 = (x0 ^ hy0) & 16383u;
      unsigned i10 = ((x0 + 1u) ^ hy0) & 16383u;
      unsigned i01 = (x0 ^ hy1) & 16383u;
      unsigned i11 = ((x0 + 1u) ^ hy1) & 16383u;
      union { unsigned u; _Float16 h[2]; } e00, e10, e01, e11;
      e00.u = smem[i00]; e10.u = smem[i10];
      e01.u = smem[i01]; e11.u = smem[i11];
      float wx0 = 1.0f - fx;
      float w00 = wx0 * wy0, w10 = fx * wy0, w01 = wx0 * fy, w11 = fx * fy;
      float gx = w00 * (float)e00.h[0] + w10 * (float)e10.h[0]
               + w01 * (float)e01.h[0] + w11 * (float)e11.h[0];
      float gy = w00 * (float)e00.h[1] + w10 * (float)e10.h[1]
               + w01 * (float)e01.h[1] + w11 * (float)e11.h[1];
      int tile = pg * 512 + xo * 16 + th;
      *(unsigned*)&ghf[(size_t)tile * 512 + (gg * 16 + cc) * 8 + sub] =
          pk_rne(gx, gy);
    }
    return;
  }

  // ---------------- style chain (float views into smem) ----------------
  float* F    = (float*)smem;
  float* xs   = F;            // 512
  float* sA   = F + 512;      // 256
  float* sB   = F + 768;      // 256
  float* st0  = F + 1024;     // 32
  float* scf  = F + 1056;     // 32
  float* st1  = F + 1088;     // 64
  float* st2  = F + 1152;     // 64
  float* dm0  = F + 1216;     // 64
  float* dm1  = F + 1280;     // 64
  float* dm2  = F + 1344;     // 4
  float* part = F + 2048;     // 4096

  const int b = blockIdx.x;

  xs[t] = z[b * 512 + t];
  __syncthreads();

  map_layer(xs, sA, mw0, mb0, 512, t, part);   // layer0
  map_layer(sA, sB, mw1, mb1, 256, t, part);   // layer1
  map_layer(sB, xs, mw2, mb2, 256, t, part);   // layer2 -> xs[0..255] = s
  const float* ss = xs;

  // ---- proj A: w_mod & a0w (K=256, N=32), 64 chunks x 4 rows ----
  {
    const int jg = (t & 7) * 4, kc = t >> 3, kb = kc * 4;
    f4 wmr[4], awr[4];
#pragma unroll
    for (int k = 0; k < 4; ++k) wmr[k] = *(const f4*)&w_mod[(kb + k) * 32 + jg];
#pragma unroll
    for (int k = 0; k < 4; ++k) awr[k] = *(const f4*)&a0w[(kb + k) * 32 + jg];
    f4 am = {0,0,0,0}, as = {0,0,0,0};
#pragma unroll
    for (int k = 0; k < 4; ++k) {
      float sv = ss[kb + k];
      am += sv * wmr[k]; as += sv * awr[k];
    }
    *(f4*)&part[kc * 32 + jg] = am;
    *(f4*)&part[2048 + kc * 32 + jg] = as;
  }
  __syncthreads();
  if (t < 32) {
    float am = b_mod[t], as = a0b[t];
#pragma unroll
    for (int q = 0; q < 64; ++q) { am += part[q * 32 + t]; as += part[2048 + q * 32 + t]; }
    scf[t] = 1.0f + am; st0[t] = as;
  }
  __syncthreads();

  // ---- proj B: a1w & a2w (K=256, N=64), 32 chunks x 8 rows ----
  {
    const int jg = (t & 15) * 4, kc = t >> 4, kb = kc * 8;
    f4 w1r[8], w2r[8];
#pragma unroll
    for (int k = 0; k < 8; ++k) w1r[k] = *(const f4*)&a1w[(kb + k) * 64 + jg];
#pragma unroll
    for (int k = 0; k < 8; ++k) w2r[k] = *(const f4*)&a2w[(kb + k) * 64 + jg];
    f4 v1 = {0,0,0,0}, v2 = {0,0,0,0};
#pragma unroll
    for (int k = 0; k < 8; ++k) {
      float sv = ss[kb + k];
      v1 += sv * w1r[k]; v2 += sv * w2r[k];
    }
    *(f4*)&part[kc * 64 + jg] = v1;
    *(f4*)&part[2048 + kc * 64 + jg] = v2;
  }
  __syncthreads();
  if (t >= 128 && t < 192) {
    int j = t - 128;
    float v1 = a1b[j], v2 = a2b[j];
#pragma unroll
    for (int q = 0; q < 32; ++q) { v1 += part[q * 64 + j]; v2 += part[2048 + q * 64 + j]; }
    st1[j] = v1; st2[j] = v2;
  }
  __syncthreads();

  // ---- demod partials (disjoint part regions; dm2 overlaps t<64 serially) --
  if (t < 256) {
    int j = t & 63, q = t >> 6;
    float wv[8];
#pragma unroll
    for (int i = 0; i < 8; ++i) wv[i] = w0[(q * 8 + i) * 64 + j];
    float acc = (q == 0) ? 1e-8f : 0.f;
#pragma unroll
    for (int i = 0; i < 8; ++i) {
      float p = st0[q * 8 + i] * wv[i]; acc = fmaf(p, p, acc);
    }
    part[t] = acc;                       // [0,256)
  } else {
    int u = t - 256, j = u & 63, q = u >> 6;   // 4 chunks x 16 rows
    float wv[16];
#pragma unroll
    for (int k = 0; k < 16; ++k) wv[k] = w1[(q * 16 + k) * 64 + j];
    float acc = (q == 0) ? 1e-8f : 0.f;
#pragma unroll
    for (int k = 0; k < 16; ++k) {
      float p = st1[q * 16 + k] * wv[k]; acc = fmaf(p, p, acc);
    }
    part[256 + u] = acc;                 // [256,512)
  }
  if (t < 64) {                          // dm2: 16 chunks x 4 rows
    int ch = t & 3, q = t >> 2;
    if (ch < 3) {
      float wv[4];
#pragma unroll
      for (int k = 0; k < 4; ++k) wv[k] = w2[(q * 4 + k) * 3 + ch];
      float acc = (q == 0) ? 1e-8f : 0.f;
#pragma unroll
      for (int k = 0; k < 4; ++k) {
        float p = st2[q * 4 + k] * wv[k]; acc = fmaf(p, p, acc);
      }
      part[512 + t] = acc;               // [512,576)
    }
  }
  __syncthreads();
  if (t < 64) {
    float a = part[t] + part[64 + t] + part[128 + t] + part[192 + t];
    dm0[t] = 1.0f / sqrtf(a);
  } else if (t < 128) {
    int j = t - 64; float a = 0.f;
#pragma unroll
    for (int q = 0; q < 4; ++q) a += part[256 + q * 64 + j];
    dm1[j] = 1.0f / sqrtf(a);
  } else if (t >= 192 && t < 195) {
    int ch = t - 192; float a = 0.f;
#pragma unroll
    for (int q = 0; q < 16; ++q) a += part[512 + q * 4 + ch];
    dm2[ch] = 1.0f / sqrtf(a);
  }
  __syncthreads();

  // ---- fold effective f16 weights ----
  for (int f = t; f < 2048; f += 512) {
    int j = f >> 5, i = f & 31;
    W0h[b * 2048 + f] = (_Float16)(scf[i] * st0[i] * w0[i * 64 + j] * dm0[j]);
  }
  for (int f = t; f < 4096; f += 512) {
    int j2 = f >> 6, k = f & 63;
    W1h[b * 4096 + f] = (_Float16)(GAINF * st1[k] * w1[k * 64 + j2] * dm1[j2]);
  }
  for (int f = t; f < 1024; f += 512) {
    int ch = f >> 6, k = f & 63;
    W2h[b * 1024 + f] = (ch < 3) ? (_Float16)(GAINF * st2[k] * w2[k * 3 + ch] * dm2[ch])
                                 : (_Float16)0.0f;
  }
}

// ---------------- LDS activation staging helpers ----------------------------
__device__ __forceinline__ void st4(_Float16* L, int pix, int jb, f4 v) {
  int ks = jb ^ ((pix & 7) << 3);
  union { unsigned u[2]; uint2 v2; } U;
  U.u[0] = pk(v[0], v[1]); U.u[1] = pk(v[2], v[3]);
  *(uint2*)(L + pix * 64 + ks) = U.v2;
}
__device__ __forceinline__ h8 ldf(const _Float16* L, int pix, int kb) {
  int ks = kb ^ ((pix & 7) << 3);
  return *(const h8*)(L + pix * 64 + ks);
}

// ---------------- MFMA MLP ---------------------------------------------------
template <int FUSED>
__global__ void __launch_bounds__(256) k_mlp(
    const _Float16* __restrict__ W0h, const _Float16* __restrict__ W1h,
    const _Float16* __restrict__ W2h, const _Float16* __restrict__ ghf,
    const float* __restrict__ bt,
    const float* __restrict__ bb0, const float* __restrict__ bb1,
    const float* __restrict__ bb2, float* __restrict__ out)
{
  __shared__ _Float16 lds[4][4096];
  __shared__ _Float16 hb[FUSED ? 8192 : 8];

  const int t = threadIdx.x;
  const int w = t >> 6, lane = t & 63;
  const int c = lane & 15, g = lane >> 4;
  const int b = blockIdx.y;
  const int pixb = blockIdx.x * 256 + w * 64;
  const int tile0 = pixb >> 4;
  _Float16* L = lds[w];

  if constexpr (FUSED) {
    float gl[32];
    hash_features(bt, blockIdx.x * 256 + t, gl);
    int tl = t >> 4, cl = t & 15;
#pragma unroll
    for (int gg = 0; gg < 4; ++gg) {
      union { unsigned u[4]; uint4 v; } U;
      U.u[0] = pk(gl[8 * gg + 0], gl[8 * gg + 1]);
      U.u[1] = pk(gl[8 * gg + 2], gl[8 * gg + 3]);
      U.u[2] = pk(gl[8 * gg + 4], gl[8 * gg + 5]);
      U.u[3] = pk(gl[8 * gg + 6], gl[8 * gg + 7]);
      *(uint4*)&hb[tl * 512 + (gg * 16 + cl) * 8] = U.v;
    }
    __syncthreads();
  }

  h8 A0[4], A1[4][2], A2[2];
#pragma unroll
  for (int jt = 0; jt < 4; ++jt)
    A0[jt] = *(const h8*)&W0h[b * 2048 + (jt * 16 + c) * 32 + 8 * g];
#pragma unroll
  for (int jt = 0; jt < 4; ++jt)
#pragma unroll
    for (int kf = 0; kf < 2; ++kf)
      A1[jt][kf] = *(const h8*)&W1h[b * 4096 + (jt * 16 + c) * 64 + kf * 32 + 8 * g];
#pragma unroll
  for (int kf = 0; kf < 2; ++kf)
    A2[kf] = *(const h8*)&W2h[b * 1024 + c * 64 + kf * 32 + 8 * g];

  f4 bv0[4], bv1[4], bv2;
#pragma unroll
  for (int jt = 0; jt < 4; ++jt) {
    bv0[jt] = *(const f4*)&bb0[jt * 16 + 4 * g];
    bv1[jt] = *(const f4*)&bb1[jt * 16 + 4 * g];
  }
  if (g == 0) { bv2 = f4{bb2[0], bb2[1], bb2[2], 0.0f}; }
  else        { bv2 = f4{0.0f, 0.0f, 0.0f, 0.0f}; }

  f4 acc[4][4];
#pragma unroll
  for (int pt = 0; pt < 4; ++pt) {
    h8 Bh;
    if constexpr (FUSED) {
      Bh = *(const h8*)&hb[(w * 4 + pt) * 512 + lane * 8];
    } else {
      Bh = *(const h8*)&ghf[(size_t)(tile0 + pt) * 512 + lane * 8];
    }
#pragma unroll
    for (int jt = 0; jt < 4; ++jt)
      acc[jt][pt] = MFMA16(A0[jt], Bh, bv0[jt]);
  }

#pragma unroll
  for (int jt = 0; jt < 4; ++jt)
#pragma unroll
    for (int pt = 0; pt < 4; ++pt) {
      f4 v = acc[jt][pt];
#pragma unroll
      for (int r = 0; r < 4; ++r) v[r] = act(v[r]);
      st4(L, pt * 16 + c, jt * 16 + 4 * g, v);
    }

  f4 acc1[4][4];
#pragma unroll
  for (int pt = 0; pt < 4; ++pt) {
    h8 Bf0 = ldf(L, pt * 16 + c, 0 * 32 + 8 * g);
    h8 Bf1 = ldf(L, pt * 16 + c, 1 * 32 + 8 * g);
#pragma unroll
    for (int jt = 0; jt < 4; ++jt) {
      f4 a = MFMA16(A1[jt][0], Bf0, bv1[jt]);
      acc1[jt][pt] = MFMA16(A1[jt][1], Bf1, a);
    }
  }

#pragma unroll
  for (int jt = 0; jt < 4; ++jt)
#pragma unroll
    for (int pt = 0; pt < 4; ++pt) {
      f4 v = acc1[jt][pt];
#pragma unroll
      for (int r = 0; r < 4; ++r) v[r] = act(v[r]);
      st4(L, pt * 16 + c, jt * 16 + 4 * g, v);
    }

#pragma unroll
  for (int pt = 0; pt < 4; ++pt) {
    h8 Bf0 = ldf(L, pt * 16 + c, 0 * 32 + 8 * g);
    h8 Bf1 = ldf(L, pt * 16 + c, 1 * 32 + 8 * g);
    f4 a = MFMA16(A2[0], Bf0, bv2);
    a = MFMA16(A2[1], Bf1, a);
    if (g == 0) {
      int pix = pixb + pt * 16 + c;
#pragma unroll
      for (int r = 0; r < 3; ++r)
        out[((b * 3 + r) << 16) + pix] = tanh_fast(a[r]);
    }
  }
}

// ---------------- launch -----------------------------------------------------
// ws bytes: [0,32768) W0h | [32768,98304) W1h | [98304,114688) W2h |
//           [114688,4308992) ghf
extern "C" void kernel_launch(void* const* d_in, const int* in_sizes, int n_in,
                              void* d_out, int out_size, void* d_ws, size_t ws_size,
                              hipStream_t stream)
{
  const float* z    = (const float*)d_in[0];
  const float* mw0  = (const float*)d_in[1];
  const float* mb0  = (const float*)d_in[2];
  const float* mw1  = (const float*)d_in[3];
  const float* mb1  = (const float*)d_in[4];
  const float* mw2  = (const float*)d_in[5];
  const float* mb2  = (const float*)d_in[6];
  const float* bt   = (const float*)d_in[7];
  const float* wmod = (const float*)d_in[8];
  const float* bmod = (const float*)d_in[9];
  const float* a0w  = (const float*)d_in[10];
  const float* a0b  = (const float*)d_in[11];
  const float* w0   = (const float*)d_in[12];
  const float* bb0  = (const float*)d_in[13];
  const float* a1w  = (const float*)d_in[14];
  const float* a1b  = (const float*)d_in[15];
  const float* w1   = (const float*)d_in[16];
  const float* bb1  = (const float*)d_in[17];
  const float* a2w  = (const float*)d_in[18];
  const float* a2b  = (const float*)d_in[19];
  const float* w2   = (const float*)d_in[20];
  const float* bb2  = (const float*)d_in[21];

  char* ws = (char*)d_ws;
  _Float16* W0h = (_Float16*)(ws);
  _Float16* W1h = (_Float16*)(ws + 32768);
  _Float16* W2h = (_Float16*)(ws + 98304);
  _Float16* ghf = (_Float16*)(ws + 114688);
  float* out = (float*)d_out;

  if (ws_size >= (size_t)4308992) {
    k_pre<<<8 + 128, 512, 0, stream>>>(z, mw0, mb0, mw1, mb1, mw2, mb2, bt,
                                       wmod, bmod, a0w, a0b, w0,
                                       a1w, a1b, w1, a2w, a2b, w2,
                                       W0h, W1h, W2h, ghf);
    k_mlp<0><<<dim3(256, NB), 256, 0, stream>>>(W0h, W1h, W2h, ghf, bt,
                                                bb0, bb1, bb2, out);
  } else {
    k_pre<<<8, 512, 0, stream>>>(z, mw0, mb0, mw1, mb1, mw2, mb2, bt,
                                 wmod, bmod, a0w, a0b, w0,
                                 a1w, a1b, w1, a2w, a2b, w2,
                                 W0h, W1h, W2h, ghf);
    k_mlp<1><<<dim3(256, NB), 256, 0, stream>>>(W0h, W1h, W2h, ghf, bt,
                                                bb0, bb1, bb2, out);
  }
}